// Round 1
// baseline (866.727 us; speedup 1.0000x reference)
//
#include <hip/hip_runtime.h>

// Attention_14353780703904: B=8, S=2048, D=1024, fp32 in/out.
//   proj = x @ W^T + b ; scores = x @ proj^T ; weights = softmax(scores) ;
//   ctx = weights @ x.  Outputs: [ctx (B*S*D) | weights (B*S*S)] fp32.
//
// Strategy: fp16 MFMA (16x16x32) for all GEMMs, fp32 accumulate.
// GEMM1/GEMM2 use fp16x2 split precision (hi+lo, 3 K-segments) to keep
// softmax-input score error ~1e-4 (threshold is ~2% of max|ref|).

typedef _Float16 f16;
typedef _Float16 f16x8 __attribute__((ext_vector_type(8)));
typedef _Float16 f16x4 __attribute__((ext_vector_type(4)));
typedef float f32x4 __attribute__((ext_vector_type(4)));
typedef unsigned int u32;

#define AS1 __attribute__((address_space(1)))
#define AS3 __attribute__((address_space(3)))

static constexpr int Bb = 8, Ss = 2048, Dd = 1024;

// ---------------- split cast: fp32 -> (hi, lo) fp16 ----------------
__global__ __launch_bounds__(256) void split_cast_k(
    const float* __restrict__ in, f16* __restrict__ hi, f16* __restrict__ lo,
    size_t n4) {
  size_t i = (size_t)blockIdx.x * 256 + threadIdx.x;
  if (i >= n4) return;
  float4 v = ((const float4*)in)[i];
  f16x4 h, l;
  h[0] = (f16)v.x; l[0] = (f16)(v.x - (float)h[0]);
  h[1] = (f16)v.y; l[1] = (f16)(v.y - (float)h[1]);
  h[2] = (f16)v.z; l[2] = (f16)(v.z - (float)h[2]);
  h[3] = (f16)v.w; l[3] = (f16)(v.w - (float)h[3]);
  ((f16x4*)hi)[i] = h;
  ((f16x4*)lo)[i] = l;
}

// ---------------- transpose+cast: x[b][s][d] fp32 -> xT[b][d][s] fp16 ------
__global__ __launch_bounds__(256) void transpose_cast_k(
    const float* __restrict__ x, f16* __restrict__ xT) {
  __shared__ f16 tile[32][33];
  const int b = blockIdx.z;
  const int s0 = blockIdx.x * 32, d0 = blockIdx.y * 32;
  const int tx = threadIdx.x & 31, ty = threadIdx.x >> 5;  // 32 x 8
  const float* xb = x + (size_t)b * Ss * Dd;
#pragma unroll
  for (int r = 0; r < 32; r += 8)
    tile[ty + r][tx] = (f16)xb[(size_t)(s0 + ty + r) * Dd + d0 + tx];
  __syncthreads();
  f16* xTb = xT + (size_t)b * Dd * Ss;
#pragma unroll
  for (int r = 0; r < 32; r += 8)
    xTb[(size_t)(d0 + ty + r) * Ss + s0 + tx] = tile[tx][ty + r];
}

// ---------------- stage 128x32 f16 tile (8192B) into LDS -------------------
// global_load_lds: LDS dest = wave-uniform base + lane*16.  8 chunks of
// 1024B; wave w stages chunks 2w, 2w+1.  LDS layout row-major [128][32].
__device__ __forceinline__ void stage_tile(const f16* __restrict__ g,
                                           size_t ld, f16* lds, int wave,
                                           int lane) {
#pragma unroll
  for (int c = 0; c < 2; ++c) {
    int chunk = wave * 2 + c;
    int row = chunk * 16 + (lane >> 2);
    int colh = (lane & 3) * 8;
    const f16* gp = g + (size_t)row * ld + colh;
    AS3 u32* lp = (AS3 u32*)(lds + chunk * 512);
    __builtin_amdgcn_global_load_lds((const AS1 u32*)gp, lp, 16, 0, 0);
  }
}

// ---------------- batched C = sum_seg A_seg * B_seg^T (+bias) --------------
// A: [M][K] f16 (lda=K), B: [N][K] f16 (ldb=K), C: [M][ldc] fp32 or split f16
// grid: (N/128, M/128, batch)
template <int NSEG, bool OUT_SPLIT>
__global__ __launch_bounds__(256) void gemm_bt(
    const f16* __restrict__ A0, const f16* __restrict__ A1,
    const f16* __restrict__ A2, const f16* __restrict__ B0,
    const f16* __restrict__ B1, const f16* __restrict__ B2,
    float* __restrict__ C, f16* __restrict__ Ch, f16* __restrict__ Cl,
    const float* __restrict__ bias, int K, size_t ldc, size_t sA, size_t sB,
    size_t sC) {
  const int tid = threadIdx.x;
  const int wave = tid >> 6, lane = tid & 63;
  const size_t tn = (size_t)blockIdx.x * 128;
  const size_t tm = (size_t)blockIdx.y * 128;
  const int b = blockIdx.z;

  __shared__ f16 As[128 * 32];
  __shared__ f16 Bs[128 * 32];

  const f16* Aps[3] = {A0, A1, A2};
  const f16* Bps[3] = {B0, B1, B2};

  const int wm = (wave >> 1) * 64;
  const int wn = (wave & 1) * 64;

  f32x4 acc[4][4] = {};

  for (int seg = 0; seg < NSEG; ++seg) {
    const f16* Ab = Aps[seg] + (size_t)b * sA + tm * (size_t)K;
    const f16* Bbp = Bps[seg] + (size_t)b * sB + tn * (size_t)K;
    for (int k0 = 0; k0 < K; k0 += 32) {
      __syncthreads();  // previous iter's fragment reads complete
      stage_tile(Ab + k0, K, As, wave, lane);
      stage_tile(Bbp + k0, K, Bs, wave, lane);
      __syncthreads();  // staging complete (compiler emits vmcnt(0) drain)
      f16x8 af[4], bf[4];
#pragma unroll
      for (int i = 0; i < 4; ++i) {
        af[i] = *(const f16x8*)&As[(wm + i * 16 + (lane & 15)) * 32 +
                                   (lane >> 4) * 8];
        bf[i] = *(const f16x8*)&Bs[(wn + i * 16 + (lane & 15)) * 32 +
                                   (lane >> 4) * 8];
      }
#pragma unroll
      for (int i = 0; i < 4; ++i)
#pragma unroll
        for (int j = 0; j < 4; ++j)
          acc[i][j] = __builtin_amdgcn_mfma_f32_16x16x32_f16(af[i], bf[j],
                                                             acc[i][j], 0, 0, 0);
    }
  }

  // epilogue: C/D layout col = lane&15, row = (lane>>4)*4 + reg
#pragma unroll
  for (int i = 0; i < 4; ++i) {
    size_t row0 = tm + wm + i * 16 + ((lane >> 4) << 2);
#pragma unroll
    for (int j = 0; j < 4; ++j) {
      size_t col = tn + wn + j * 16 + (lane & 15);
      float bj = bias ? bias[col] : 0.f;
#pragma unroll
      for (int r = 0; r < 4; ++r) {
        float v = acc[i][j][r] + bj;
        size_t off = (size_t)b * sC + (row0 + r) * ldc + col;
        if constexpr (OUT_SPLIT) {
          f16 h = (f16)v;
          Ch[off] = h;
          Cl[off] = (f16)(v - (float)h);
        } else {
          C[off] = v;
        }
      }
    }
  }
}

// ---------------- row softmax (2048 cols), in-place fp32 + f16 copy --------
__global__ __launch_bounds__(256) void softmax_k(float* __restrict__ sc,
                                                 f16* __restrict__ wh) {
  const size_t row = blockIdx.x;
  float* p = sc + row * 2048;
  f16* w = wh + row * 2048;
  const int t = threadIdx.x;
  float4 v0 = ((const float4*)p)[t];
  float4 v1 = ((const float4*)p)[256 + t];
  float m = fmaxf(fmaxf(fmaxf(v0.x, v0.y), fmaxf(v0.z, v0.w)),
                  fmaxf(fmaxf(v1.x, v1.y), fmaxf(v1.z, v1.w)));
#pragma unroll
  for (int o = 32; o; o >>= 1) m = fmaxf(m, __shfl_xor(m, o, 64));
  __shared__ float red[4];
  if ((t & 63) == 0) red[t >> 6] = m;
  __syncthreads();
  m = fmaxf(fmaxf(red[0], red[1]), fmaxf(red[2], red[3]));
  v0.x = __expf(v0.x - m);
  v0.y = __expf(v0.y - m);
  v0.z = __expf(v0.z - m);
  v0.w = __expf(v0.w - m);
  v1.x = __expf(v1.x - m);
  v1.y = __expf(v1.y - m);
  v1.z = __expf(v1.z - m);
  v1.w = __expf(v1.w - m);
  float s = v0.x + v0.y + v0.z + v0.w + v1.x + v1.y + v1.z + v1.w;
#pragma unroll
  for (int o = 32; o; o >>= 1) s += __shfl_xor(s, o, 64);
  __shared__ float red2[4];
  if ((t & 63) == 0) red2[t >> 6] = s;
  __syncthreads();
  s = red2[0] + red2[1] + red2[2] + red2[3];
  float inv = 1.0f / s;
  v0.x *= inv; v0.y *= inv; v0.z *= inv; v0.w *= inv;
  v1.x *= inv; v1.y *= inv; v1.z *= inv; v1.w *= inv;
  ((float4*)p)[t] = v0;
  ((float4*)p)[256 + t] = v1;
  f16x4 h0, h1;
  h0[0] = (f16)v0.x; h0[1] = (f16)v0.y; h0[2] = (f16)v0.z; h0[3] = (f16)v0.w;
  h1[0] = (f16)v1.x; h1[1] = (f16)v1.y; h1[2] = (f16)v1.z; h1[3] = (f16)v1.w;
  ((f16x4*)w)[t] = h0;
  ((f16x4*)w)[256 + t] = h1;
}

extern "C" void kernel_launch(void* const* d_in, const int* in_sizes, int n_in,
                              void* d_out, int out_size, void* d_ws,
                              size_t ws_size, hipStream_t stream) {
  (void)in_sizes; (void)n_in; (void)out_size; (void)ws_size;
  const float* x = (const float*)d_in[0];     // [B,S,D]
  const float* W = (const float*)d_in[1];     // [D,D]
  const float* bias = (const float*)d_in[2];  // [D]
  float* ctx = (float*)d_out;                           // [B,S,D]
  float* scores = (float*)d_out + (size_t)Bb * Ss * Dd; // [B,S,S]

  const size_t nBSD = (size_t)Bb * Ss * Dd;  // 16,777,216
  const size_t nDD = (size_t)Dd * Dd;        // 1,048,576

  f16* p = (f16*)d_ws;
  f16* x_hi = p; p += nBSD;
  f16* x_lo = p; p += nBSD;
  f16* xT   = p; p += nBSD;
  f16* W_hi = p; p += nDD;
  f16* W_lo = p; p += nDD;
  f16* p_hi = p; p += nBSD;
  f16* p_lo = p; p += nBSD;
  f16* attnw = p_hi;  // aliases p_hi..p_lo (dead after GEMM2); B*S*S halfs
  // total ws use: (5*nBSD + 2*nDD)*2 bytes = ~172 MB

  // casts
  split_cast_k<<<(unsigned)(nBSD / 4 / 256), 256, 0, stream>>>(x, x_hi, x_lo,
                                                               nBSD / 4);
  split_cast_k<<<(unsigned)(nDD / 4 / 256), 256, 0, stream>>>(W, W_hi, W_lo,
                                                              nDD / 4);
  transpose_cast_k<<<dim3(Ss / 32, Dd / 32, Bb), 256, 0, stream>>>(x, xT);

  // GEMM1: proj = x @ W^T + b  (split in, split out)  M=B*S, N=D, K=D
  gemm_bt<3, true><<<dim3(Dd / 128, (Bb * Ss) / 128, 1), 256, 0, stream>>>(
      x_hi, x_lo, x_hi, W_hi, W_hi, W_lo, nullptr, p_hi, p_lo, bias, Dd,
      (size_t)Dd, 0, 0, 0);

  // GEMM2: scores[b] = x[b] @ proj[b]^T  (split in, fp32 out)  M=N=S, K=D
  gemm_bt<3, false><<<dim3(Ss / 128, Ss / 128, Bb), 256, 0, stream>>>(
      x_hi, x_lo, x_hi, p_hi, p_hi, p_lo, scores, nullptr, nullptr, nullptr,
      Dd, (size_t)Ss, (size_t)Ss * Dd, (size_t)Ss * Dd, (size_t)Ss * Ss);

  // softmax rows, in-place + f16 copy
  softmax_k<<<Bb * Ss, 256, 0, stream>>>(scores, attnw);

  // GEMM4: ctx[b] = weights[b] @ x[b]  via B = xT[b] ([D][S])  M=S, N=D, K=S
  gemm_bt<1, false><<<dim3(Dd / 128, Ss / 128, Bb), 256, 0, stream>>>(
      attnw, nullptr, nullptr, xT, nullptr, nullptr, ctx, nullptr, nullptr,
      nullptr, Ss, (size_t)Dd, (size_t)Ss * Ss, (size_t)Dd * Ss,
      (size_t)Ss * Dd);
}

// Round 2
// 805.097 us; speedup vs baseline: 1.0765x; 1.0765x over previous
//
#include <hip/hip_runtime.h>

// Attention_14353780703904: B=8, S=2048, D=1024, fp32 in/out.
//   proj = x @ W^T + b ; scores = x @ proj^T ; weights = softmax(scores) ;
//   ctx = weights @ x.  Outputs: [ctx (B*S*D) | weights (B*S*S)] fp32.
//
// R2: fragment-order LDS staging (zero bank conflicts: ds_read_b128 at
// base+lane*16) + dual-A/shared-B split precision (x = hi+lo f16, B staged
// once per k-step). Scores = (x_hi+x_lo)@p_hi^T — residual x@p_lo ~1e-2 max.

typedef _Float16 f16;
typedef _Float16 f16x8 __attribute__((ext_vector_type(8)));
typedef _Float16 f16x4 __attribute__((ext_vector_type(4)));
typedef float f32x4 __attribute__((ext_vector_type(4)));
typedef unsigned int u32;

#define AS1 __attribute__((address_space(1)))
#define AS3 __attribute__((address_space(3)))

static constexpr int Bb = 8, Ss = 2048, Dd = 1024;

// ---------------- split cast: fp32 -> (hi, lo) fp16 ----------------
__global__ __launch_bounds__(256) void split_cast_k(
    const float* __restrict__ in, f16* __restrict__ hi, f16* __restrict__ lo,
    size_t n4) {
  size_t i = (size_t)blockIdx.x * 256 + threadIdx.x;
  if (i >= n4) return;
  float4 v = ((const float4*)in)[i];
  f16x4 h, l;
  h[0] = (f16)v.x; l[0] = (f16)(v.x - (float)h[0]);
  h[1] = (f16)v.y; l[1] = (f16)(v.y - (float)h[1]);
  h[2] = (f16)v.z; l[2] = (f16)(v.z - (float)h[2]);
  h[3] = (f16)v.w; l[3] = (f16)(v.w - (float)h[3]);
  ((f16x4*)hi)[i] = h;
  ((f16x4*)lo)[i] = l;
}

// ---------------- plain cast: fp32 -> fp16 ----------------
__global__ __launch_bounds__(256) void cast_k(const float* __restrict__ in,
                                              f16* __restrict__ out,
                                              size_t n4) {
  size_t i = (size_t)blockIdx.x * 256 + threadIdx.x;
  if (i >= n4) return;
  float4 v = ((const float4*)in)[i];
  f16x4 h;
  h[0] = (f16)v.x; h[1] = (f16)v.y; h[2] = (f16)v.z; h[3] = (f16)v.w;
  ((f16x4*)out)[i] = h;
}

// ---------------- transpose+cast: x[b][s][d] fp32 -> xT[b][d][s] fp16 ------
__global__ __launch_bounds__(256) void transpose_cast_k(
    const float* __restrict__ x, f16* __restrict__ xT) {
  __shared__ f16 tile[32][33];
  const int b = blockIdx.z;
  const int s0 = blockIdx.x * 32, d0 = blockIdx.y * 32;
  const int tx = threadIdx.x & 31, ty = threadIdx.x >> 5;  // 32 x 8
  const float* xb = x + (size_t)b * Ss * Dd;
#pragma unroll
  for (int r = 0; r < 32; r += 8)
    tile[ty + r][tx] = (f16)xb[(size_t)(s0 + ty + r) * Dd + d0 + tx];
  __syncthreads();
  f16* xTb = xT + (size_t)b * Dd * Ss;
#pragma unroll
  for (int r = 0; r < 32; r += 8)
    xTb[(size_t)(d0 + ty + r) * Ss + s0 + tx] = tile[tx][ty + r];
}

// ---------------- stage 128x32 f16 tile in MFMA-fragment order -------------
// Panel p = 16 rows x 32 k = 1024B, stored so lane l holds element
// (row p*16+(l&15), k (l>>4)*8 .. +7) at panel_base + l*16.  Fragment
// reads are then ds_read_b128 at base+lane*16: zero bank conflicts.
// Global side: 16 rows x 64B contiguous per instruction (fully coalesced).
__device__ __forceinline__ void stage_tile(const f16* __restrict__ g,
                                           size_t ld, f16* lds, int wave,
                                           int lane) {
#pragma unroll
  for (int c = 0; c < 2; ++c) {
    int panel = wave * 2 + c;
    const f16* gp =
        g + (size_t)(panel * 16 + (lane & 15)) * ld + (lane >> 4) * 8;
    AS3 u32* lp = (AS3 u32*)(lds + panel * 512);
    __builtin_amdgcn_global_load_lds((const AS1 u32*)gp, lp, 16, 0, 0);
  }
}

// ---------------- batched C = A * B^T (+bias) ------------------------------
// DUAL_A: C = (A0 + A1) * B0^T (two A segments share one staged B tile).
// A: [M][K] f16, B: [N][K] f16, C fp32 [M][ldc] or f16 (OUT_F16).
// grid: (N/128, M/128, batch); 4 waves in 2x2, 64x64 per wave.
template <bool DUAL_A, bool OUT_F16>
__global__ __launch_bounds__(256) void gemm_bt(
    const f16* __restrict__ A0, const f16* __restrict__ A1,
    const f16* __restrict__ B0, float* __restrict__ C, f16* __restrict__ Ch,
    const float* __restrict__ bias, int K, size_t ldc, size_t sA, size_t sB,
    size_t sC) {
  const int tid = threadIdx.x;
  const int wave = tid >> 6, lane = tid & 63;
  const size_t tn = (size_t)blockIdx.x * 128;
  const size_t tm = (size_t)blockIdx.y * 128;
  const int b = blockIdx.z;

  __shared__ f16 smem[(DUAL_A ? 3 : 2) * 4096];
  f16* Ash = smem;
  f16* Asl = smem + 4096;  // only used when DUAL_A
  f16* Bs = smem + (DUAL_A ? 8192 : 4096);

  const f16* Ah = A0 + (size_t)b * sA + tm * (size_t)K;
  const f16* Al = DUAL_A ? (A1 + (size_t)b * sA + tm * (size_t)K) : nullptr;
  const f16* Bp = B0 + (size_t)b * sB + tn * (size_t)K;

  const int pA = (wave >> 1) * 4;  // this wave's A panels [pA, pA+4)
  const int pB = (wave & 1) * 4;   // this wave's B panels

  f32x4 acc[4][4] = {};

  for (int k0 = 0; k0 < K; k0 += 32) {
    __syncthreads();  // previous iter's fragment reads complete
    stage_tile(Ah + k0, K, Ash, wave, lane);
    if constexpr (DUAL_A) stage_tile(Al + k0, K, Asl, wave, lane);
    stage_tile(Bp + k0, K, Bs, wave, lane);
    __syncthreads();  // staging complete
    f16x8 bf[4];
#pragma unroll
    for (int j = 0; j < 4; ++j)
      bf[j] = *(const f16x8*)&Bs[(pB + j) * 512 + lane * 8];
#pragma unroll
    for (int i = 0; i < 4; ++i) {
      f16x8 af = *(const f16x8*)&Ash[(pA + i) * 512 + lane * 8];
#pragma unroll
      for (int j = 0; j < 4; ++j)
        acc[i][j] =
            __builtin_amdgcn_mfma_f32_16x16x32_f16(af, bf[j], acc[i][j], 0, 0, 0);
      if constexpr (DUAL_A) {
        f16x8 al = *(const f16x8*)&Asl[(pA + i) * 512 + lane * 8];
#pragma unroll
        for (int j = 0; j < 4; ++j)
          acc[i][j] = __builtin_amdgcn_mfma_f32_16x16x32_f16(al, bf[j],
                                                             acc[i][j], 0, 0, 0);
      }
    }
  }

  // epilogue: C/D layout col = lane&15, row = (lane>>4)*4 + reg
  const int wm = pA * 16, wn = pB * 16;
#pragma unroll
  for (int i = 0; i < 4; ++i) {
    size_t row0 = tm + wm + i * 16 + ((lane >> 4) << 2);
#pragma unroll
    for (int j = 0; j < 4; ++j) {
      size_t col = tn + wn + j * 16 + (lane & 15);
      float bj = bias ? bias[col] : 0.f;
#pragma unroll
      for (int r = 0; r < 4; ++r) {
        float v = acc[i][j][r] + bj;
        size_t off = (size_t)b * sC + (row0 + r) * ldc + col;
        if constexpr (OUT_F16)
          Ch[off] = (f16)v;
        else
          C[off] = v;
      }
    }
  }
}

// ---------------- row softmax (2048 cols), in-place fp32 + f16 copy --------
__global__ __launch_bounds__(256) void softmax_k(float* __restrict__ sc,
                                                 f16* __restrict__ wh) {
  const size_t row = blockIdx.x;
  float* p = sc + row * 2048;
  f16* w = wh + row * 2048;
  const int t = threadIdx.x;
  float4 v0 = ((const float4*)p)[t];
  float4 v1 = ((const float4*)p)[256 + t];
  float m = fmaxf(fmaxf(fmaxf(v0.x, v0.y), fmaxf(v0.z, v0.w)),
                  fmaxf(fmaxf(v1.x, v1.y), fmaxf(v1.z, v1.w)));
#pragma unroll
  for (int o = 32; o; o >>= 1) m = fmaxf(m, __shfl_xor(m, o, 64));
  __shared__ float red[4];
  if ((t & 63) == 0) red[t >> 6] = m;
  __syncthreads();
  m = fmaxf(fmaxf(red[0], red[1]), fmaxf(red[2], red[3]));
  v0.x = __expf(v0.x - m);
  v0.y = __expf(v0.y - m);
  v0.z = __expf(v0.z - m);
  v0.w = __expf(v0.w - m);
  v1.x = __expf(v1.x - m);
  v1.y = __expf(v1.y - m);
  v1.z = __expf(v1.z - m);
  v1.w = __expf(v1.w - m);
  float s = v0.x + v0.y + v0.z + v0.w + v1.x + v1.y + v1.z + v1.w;
#pragma unroll
  for (int o = 32; o; o >>= 1) s += __shfl_xor(s, o, 64);
  __shared__ float red2[4];
  if ((t & 63) == 0) red2[t >> 6] = s;
  __syncthreads();
  s = red2[0] + red2[1] + red2[2] + red2[3];
  float inv = 1.0f / s;
  v0.x *= inv; v0.y *= inv; v0.z *= inv; v0.w *= inv;
  v1.x *= inv; v1.y *= inv; v1.z *= inv; v1.w *= inv;
  ((float4*)p)[t] = v0;
  ((float4*)p)[256 + t] = v1;
  f16x4 h0, h1;
  h0[0] = (f16)v0.x; h0[1] = (f16)v0.y; h0[2] = (f16)v0.z; h0[3] = (f16)v0.w;
  h1[0] = (f16)v1.x; h1[1] = (f16)v1.y; h1[2] = (f16)v1.z; h1[3] = (f16)v1.w;
  ((f16x4*)w)[t] = h0;
  ((f16x4*)w)[256 + t] = h1;
}

extern "C" void kernel_launch(void* const* d_in, const int* in_sizes, int n_in,
                              void* d_out, int out_size, void* d_ws,
                              size_t ws_size, hipStream_t stream) {
  (void)in_sizes; (void)n_in; (void)out_size; (void)ws_size;
  const float* x = (const float*)d_in[0];     // [B,S,D]
  const float* W = (const float*)d_in[1];     // [D,D]
  const float* bias = (const float*)d_in[2];  // [D]
  float* ctx = (float*)d_out;                            // [B,S,D]
  float* scores = (float*)d_out + (size_t)Bb * Ss * Dd;  // [B,S,S]

  const size_t nBSD = (size_t)Bb * Ss * Dd;  // 16,777,216
  const size_t nDD = (size_t)Dd * Dd;        // 1,048,576

  f16* p = (f16*)d_ws;
  f16* x_hi = p; p += nBSD;
  f16* x_lo = p; p += nBSD;
  f16* xT   = p; p += nBSD;
  f16* W_hi = p; p += nDD;
  f16* p_hi = p; p += nBSD;
  // attnw [B,S,S] f16 aliases x_hi+x_lo (dead after GEMM2; exact size match)
  f16* attnw = x_hi;
  // total ws use: (4*nBSD + nDD)*2 bytes = ~136 MB

  // casts
  split_cast_k<<<(unsigned)(nBSD / 4 / 256), 256, 0, stream>>>(x, x_hi, x_lo,
                                                               nBSD / 4);
  cast_k<<<(unsigned)(nDD / 4 / 256), 256, 0, stream>>>(W, W_hi, nDD / 4);
  transpose_cast_k<<<dim3(Ss / 32, Dd / 32, Bb), 256, 0, stream>>>(x, xT);

  // GEMM1: proj = (x_hi + x_lo) @ W_hi^T + b -> f16   M=B*S, N=D, K=D
  gemm_bt<true, true><<<dim3(Dd / 128, (Bb * Ss) / 128, 1), 256, 0, stream>>>(
      x_hi, x_lo, W_hi, nullptr, p_hi, bias, Dd, (size_t)Dd, 0, 0, 0);

  // GEMM2: scores[b] = (x_hi + x_lo)[b] @ p_hi[b]^T -> fp32   M=N=S, K=D
  gemm_bt<true, false><<<dim3(Ss / 128, Ss / 128, Bb), 256, 0, stream>>>(
      x_hi, x_lo, p_hi, scores, nullptr, nullptr, Dd, (size_t)Ss,
      (size_t)Ss * Dd, (size_t)Ss * Dd, (size_t)Ss * Ss);

  // softmax rows, in-place fp32 + f16 copy (into attnw, aliasing dead x_hi)
  softmax_k<<<Bb * Ss, 256, 0, stream>>>(scores, attnw);

  // GEMM4: ctx[b] = attnw[b] @ xT[b]  (B = xT [D][S])   M=S, N=D, K=S
  gemm_bt<false, false><<<dim3(Dd / 128, Ss / 128, Bb), 256, 0, stream>>>(
      attnw, nullptr, xT, ctx, nullptr, nullptr, Ss, (size_t)Dd,
      (size_t)Ss * Ss, (size_t)Dd * Ss, (size_t)Ss * Dd);
}

// Round 3
// 626.477 us; speedup vs baseline: 1.3835x; 1.2851x over previous
//
#include <hip/hip_runtime.h>

// Attention_14353780703904: B=8, S=2048, D=1024, fp32 in/out.
//   proj = x @ W^T + b ; scores = x @ proj^T ; weights = softmax(scores) ;
//   ctx = weights @ x.  Outputs: [ctx (B*S*D) | weights (B*S*S)] fp32.
//
// R3: LDS-bandwidth fix. Wave tile 64x64 -> 64x128 (block 128x256) halves
// LDS read bytes/MAC (2(M+N)/MN: 0.0625 -> 0.047) and doubles MFMA work per
// barrier. R2 measured: conflicts 0 but MfmaUtil 26% == LDS-BW-bound model.

typedef _Float16 f16;
typedef _Float16 f16x8 __attribute__((ext_vector_type(8)));
typedef _Float16 f16x4 __attribute__((ext_vector_type(4)));
typedef float f32x4 __attribute__((ext_vector_type(4)));
typedef unsigned int u32;

#define AS1 __attribute__((address_space(1)))
#define AS3 __attribute__((address_space(3)))

static constexpr int Bb = 8, Ss = 2048, Dd = 1024;

// ---------------- split cast: fp32 -> (hi, lo) fp16 ----------------
__global__ __launch_bounds__(256) void split_cast_k(
    const float* __restrict__ in, f16* __restrict__ hi, f16* __restrict__ lo,
    size_t n4) {
  size_t i = (size_t)blockIdx.x * 256 + threadIdx.x;
  if (i >= n4) return;
  float4 v = ((const float4*)in)[i];
  f16x4 h, l;
  h[0] = (f16)v.x; l[0] = (f16)(v.x - (float)h[0]);
  h[1] = (f16)v.y; l[1] = (f16)(v.y - (float)h[1]);
  h[2] = (f16)v.z; l[2] = (f16)(v.z - (float)h[2]);
  h[3] = (f16)v.w; l[3] = (f16)(v.w - (float)h[3]);
  ((f16x4*)hi)[i] = h;
  ((f16x4*)lo)[i] = l;
}

// ---------------- plain cast: fp32 -> fp16 ----------------
__global__ __launch_bounds__(256) void cast_k(const float* __restrict__ in,
                                              f16* __restrict__ out,
                                              size_t n4) {
  size_t i = (size_t)blockIdx.x * 256 + threadIdx.x;
  if (i >= n4) return;
  float4 v = ((const float4*)in)[i];
  f16x4 h;
  h[0] = (f16)v.x; h[1] = (f16)v.y; h[2] = (f16)v.z; h[3] = (f16)v.w;
  ((f16x4*)out)[i] = h;
}

// ---------------- transpose+cast: x[b][s][d] fp32 -> xT[b][d][s] fp16 ------
__global__ __launch_bounds__(256) void transpose_cast_k(
    const float* __restrict__ x, f16* __restrict__ xT) {
  __shared__ f16 tile[32][33];
  const int b = blockIdx.z;
  const int s0 = blockIdx.x * 32, d0 = blockIdx.y * 32;
  const int tx = threadIdx.x & 31, ty = threadIdx.x >> 5;  // 32 x 8
  const float* xb = x + (size_t)b * Ss * Dd;
#pragma unroll
  for (int r = 0; r < 32; r += 8)
    tile[ty + r][tx] = (f16)xb[(size_t)(s0 + ty + r) * Dd + d0 + tx];
  __syncthreads();
  f16* xTb = xT + (size_t)b * Dd * Ss;
#pragma unroll
  for (int r = 0; r < 32; r += 8)
    xTb[(size_t)(d0 + ty + r) * Ss + s0 + tx] = tile[tx][ty + r];
}

// ---------------- stage ROWSx32 f16 tile in MFMA-fragment order ------------
// Panel p = 16 rows x 32 k = 1024B, stored so lane l holds element
// (row p*16+(l&15), k (l>>4)*8 .. +7) at panel_base + l*16.  Fragment
// reads are then ds_read_b128 at base+lane*16: zero bank conflicts
// (verified R2). Global side: 16 rows x 64B per instruction.
template <int PPW>  // panels staged per wave (tile rows = PPW*64)
__device__ __forceinline__ void stage_tile(const f16* __restrict__ g,
                                           size_t ld, f16* lds, int wave,
                                           int lane) {
#pragma unroll
  for (int c = 0; c < PPW; ++c) {
    int panel = wave * PPW + c;
    const f16* gp =
        g + (size_t)(panel * 16 + (lane & 15)) * ld + (lane >> 4) * 8;
    AS3 u32* lp = (AS3 u32*)(lds + panel * 512);
    __builtin_amdgcn_global_load_lds((const AS1 u32*)gp, lp, 16, 0, 0);
  }
}

// ---------------- batched C = A * B^T (+bias) ------------------------------
// DUAL_A: C = (A0 + A1) * B0^T (two A segments share one staged B tile).
// A: [M][K] f16, B: [N][K] f16, C fp32 [M][ldc] or f16 (OUT_F16).
// Block tile 128(M) x 256(N), BK=32; 4 waves 2x2, wave tile 64x128.
// grid: (N/256, M/128, batch).
template <bool DUAL_A, bool OUT_F16>
__global__ __launch_bounds__(256, 2) void gemm_bt(
    const f16* __restrict__ A0, const f16* __restrict__ A1,
    const f16* __restrict__ B0, float* __restrict__ C, f16* __restrict__ Ch,
    const float* __restrict__ bias, int K, size_t ldc, size_t sA, size_t sB,
    size_t sC) {
  const int tid = threadIdx.x;
  const int wave = tid >> 6, lane = tid & 63;
  const size_t tn = (size_t)blockIdx.x * 256;
  const size_t tm = (size_t)blockIdx.y * 128;
  const int b = blockIdx.z;

  __shared__ f16 smem[(DUAL_A ? 4 : 3) * 4096];
  f16* Ash = smem;                          // 128x32, 8 panels
  f16* Asl = smem + 4096;                   // only when DUAL_A
  f16* Bs = smem + (DUAL_A ? 8192 : 4096);  // 256x32, 16 panels

  const f16* Ah = A0 + (size_t)b * sA + tm * (size_t)K;
  const f16* Al = DUAL_A ? (A1 + (size_t)b * sA + tm * (size_t)K) : nullptr;
  const f16* Bp = B0 + (size_t)b * sB + tn * (size_t)K;

  const int pA = (wave >> 1) * 4;  // A panels [pA, pA+4)   (64 rows)
  const int pB = (wave & 1) * 8;   // B panels [pB, pB+8)   (128 cols)

  f32x4 acc[4][8] = {};

  for (int k0 = 0; k0 < K; k0 += 32) {
    __syncthreads();  // previous iter's fragment reads complete
    stage_tile<2>(Ah + k0, K, Ash, wave, lane);
    if constexpr (DUAL_A) stage_tile<2>(Al + k0, K, Asl, wave, lane);
    stage_tile<4>(Bp + k0, K, Bs, wave, lane);
    __syncthreads();  // staging complete
    f16x8 ah[4], al[4];
#pragma unroll
    for (int i = 0; i < 4; ++i) {
      ah[i] = *(const f16x8*)&Ash[(pA + i) * 512 + lane * 8];
      if constexpr (DUAL_A)
        al[i] = *(const f16x8*)&Asl[(pA + i) * 512 + lane * 8];
    }
#pragma unroll
    for (int j = 0; j < 8; ++j) {
      f16x8 bf = *(const f16x8*)&Bs[(pB + j) * 512 + lane * 8];
#pragma unroll
      for (int i = 0; i < 4; ++i) {
        acc[i][j] =
            __builtin_amdgcn_mfma_f32_16x16x32_f16(ah[i], bf, acc[i][j], 0, 0, 0);
        if constexpr (DUAL_A)
          acc[i][j] = __builtin_amdgcn_mfma_f32_16x16x32_f16(al[i], bf,
                                                             acc[i][j], 0, 0, 0);
      }
    }
  }

  // epilogue: C/D layout col = lane&15, row = (lane>>4)*4 + reg
  const int wm = pA * 16, wn = pB * 16;
#pragma unroll
  for (int i = 0; i < 4; ++i) {
    size_t row0 = tm + wm + i * 16 + ((lane >> 4) << 2);
#pragma unroll
    for (int j = 0; j < 8; ++j) {
      size_t col = tn + wn + j * 16 + (lane & 15);
      float bj = bias ? bias[col] : 0.f;
#pragma unroll
      for (int r = 0; r < 4; ++r) {
        float v = acc[i][j][r] + bj;
        size_t off = (size_t)b * sC + (row0 + r) * ldc + col;
        if constexpr (OUT_F16)
          Ch[off] = (f16)v;
        else
          C[off] = v;
      }
    }
  }
}

// ---------------- row softmax (2048 cols), in-place fp32 + f16 copy --------
__global__ __launch_bounds__(256) void softmax_k(float* __restrict__ sc,
                                                 f16* __restrict__ wh) {
  const size_t row = blockIdx.x;
  float* p = sc + row * 2048;
  f16* w = wh + row * 2048;
  const int t = threadIdx.x;
  float4 v0 = ((const float4*)p)[t];
  float4 v1 = ((const float4*)p)[256 + t];
  float m = fmaxf(fmaxf(fmaxf(v0.x, v0.y), fmaxf(v0.z, v0.w)),
                  fmaxf(fmaxf(v1.x, v1.y), fmaxf(v1.z, v1.w)));
#pragma unroll
  for (int o = 32; o; o >>= 1) m = fmaxf(m, __shfl_xor(m, o, 64));
  __shared__ float red[4];
  if ((t & 63) == 0) red[t >> 6] = m;
  __syncthreads();
  m = fmaxf(fmaxf(red[0], red[1]), fmaxf(red[2], red[3]));
  v0.x = __expf(v0.x - m);
  v0.y = __expf(v0.y - m);
  v0.z = __expf(v0.z - m);
  v0.w = __expf(v0.w - m);
  v1.x = __expf(v1.x - m);
  v1.y = __expf(v1.y - m);
  v1.z = __expf(v1.z - m);
  v1.w = __expf(v1.w - m);
  float s = v0.x + v0.y + v0.z + v0.w + v1.x + v1.y + v1.z + v1.w;
#pragma unroll
  for (int o = 32; o; o >>= 1) s += __shfl_xor(s, o, 64);
  __shared__ float red2[4];
  if ((t & 63) == 0) red2[t >> 6] = s;
  __syncthreads();
  s = red2[0] + red2[1] + red2[2] + red2[3];
  float inv = 1.0f / s;
  v0.x *= inv; v0.y *= inv; v0.z *= inv; v0.w *= inv;
  v1.x *= inv; v1.y *= inv; v1.z *= inv; v1.w *= inv;
  ((float4*)p)[t] = v0;
  ((float4*)p)[256 + t] = v1;
  f16x4 h0, h1;
  h0[0] = (f16)v0.x; h0[1] = (f16)v0.y; h0[2] = (f16)v0.z; h0[3] = (f16)v0.w;
  h1[0] = (f16)v1.x; h1[1] = (f16)v1.y; h1[2] = (f16)v1.z; h1[3] = (f16)v1.w;
  ((f16x4*)w)[t] = h0;
  ((f16x4*)w)[256 + t] = h1;
}

extern "C" void kernel_launch(void* const* d_in, const int* in_sizes, int n_in,
                              void* d_out, int out_size, void* d_ws,
                              size_t ws_size, hipStream_t stream) {
  (void)in_sizes; (void)n_in; (void)out_size; (void)ws_size;
  const float* x = (const float*)d_in[0];     // [B,S,D]
  const float* W = (const float*)d_in[1];     // [D,D]
  const float* bias = (const float*)d_in[2];  // [D]
  float* ctx = (float*)d_out;                            // [B,S,D]
  float* scores = (float*)d_out + (size_t)Bb * Ss * Dd;  // [B,S,S]

  const size_t nBSD = (size_t)Bb * Ss * Dd;  // 16,777,216
  const size_t nDD = (size_t)Dd * Dd;        // 1,048,576

  f16* p = (f16*)d_ws;
  f16* x_hi = p; p += nBSD;
  f16* x_lo = p; p += nBSD;
  f16* xT   = p; p += nBSD;
  f16* W_hi = p; p += nDD;
  f16* p_hi = p; p += nBSD;
  // attnw [B,S,S] f16 aliases x_hi+x_lo (dead after GEMM2; exact size match)
  f16* attnw = x_hi;
  // total ws use: (4*nBSD + nDD)*2 bytes = ~136 MB

  // casts
  split_cast_k<<<(unsigned)(nBSD / 4 / 256), 256, 0, stream>>>(x, x_hi, x_lo,
                                                               nBSD / 4);
  cast_k<<<(unsigned)(nDD / 4 / 256), 256, 0, stream>>>(W, W_hi, nDD / 4);
  transpose_cast_k<<<dim3(Ss / 32, Dd / 32, Bb), 256, 0, stream>>>(x, xT);

  // GEMM1: proj = (x_hi + x_lo) @ W_hi^T + b -> f16   M=B*S, N=D, K=D
  gemm_bt<true, true><<<dim3(Dd / 256, (Bb * Ss) / 128, 1), 256, 0, stream>>>(
      x_hi, x_lo, W_hi, nullptr, p_hi, bias, Dd, (size_t)Dd, 0, 0, 0);

  // GEMM2: scores[b] = (x_hi + x_lo)[b] @ p_hi[b]^T -> fp32   M=N=S, K=D
  gemm_bt<true, false><<<dim3(Ss / 256, Ss / 128, Bb), 256, 0, stream>>>(
      x_hi, x_lo, p_hi, scores, nullptr, nullptr, Dd, (size_t)Ss,
      (size_t)Ss * Dd, (size_t)Ss * Dd, (size_t)Ss * Ss);

  // softmax rows, in-place fp32 + f16 copy (into attnw, aliasing dead x_hi)
  softmax_k<<<Bb * Ss, 256, 0, stream>>>(scores, attnw);

  // GEMM4: ctx[b] = attnw[b] @ xT[b]  (B = xT [D][S])   M=S, N=D, K=S
  gemm_bt<false, false><<<dim3(Dd / 256, Ss / 128, Bb), 256, 0, stream>>>(
      attnw, nullptr, xT, ctx, nullptr, nullptr, Ss, (size_t)Dd,
      (size_t)Ss * Ss, (size_t)Dd * Ss, (size_t)Ss * Dd);
}

// Round 4
// 624.682 us; speedup vs baseline: 1.3875x; 1.0029x over previous
//
#include <hip/hip_runtime.h>

// Attention_14353780703904: B=8, S=2048, D=1024, fp32 in/out.
//   proj = x @ W^T + b ; scores = x @ proj^T ; weights = softmax(scores) ;
//   ctx = weights @ x.  Outputs: [ctx (B*S*D) | weights (B*S*S)] fp32.
//
// R4: double-buffered LDS K-loop, ONE barrier per iter. Stage k+1 into the
// alternate buffer right after the barrier, compute k from current buffer;
// the vmcnt(0) drain at the next barrier then waits on loads that had a
// full compute phase (~1030 cyc MFMA) in flight -> HBM latency hidden.
// R3 measured: MfmaUtil 35% == exposed-latency model at 2 blocks/CU.

typedef _Float16 f16;
typedef _Float16 f16x8 __attribute__((ext_vector_type(8)));
typedef _Float16 f16x4 __attribute__((ext_vector_type(4)));
typedef float f32x4 __attribute__((ext_vector_type(4)));
typedef unsigned int u32;

#define AS1 __attribute__((address_space(1)))
#define AS3 __attribute__((address_space(3)))

static constexpr int Bb = 8, Ss = 2048, Dd = 1024;

// ---------------- split cast: fp32 -> (hi, lo) fp16 ----------------
__global__ __launch_bounds__(256) void split_cast_k(
    const float* __restrict__ in, f16* __restrict__ hi, f16* __restrict__ lo,
    size_t n4) {
  size_t i = (size_t)blockIdx.x * 256 + threadIdx.x;
  if (i >= n4) return;
  float4 v = ((const float4*)in)[i];
  f16x4 h, l;
  h[0] = (f16)v.x; l[0] = (f16)(v.x - (float)h[0]);
  h[1] = (f16)v.y; l[1] = (f16)(v.y - (float)h[1]);
  h[2] = (f16)v.z; l[2] = (f16)(v.z - (float)h[2]);
  h[3] = (f16)v.w; l[3] = (f16)(v.w - (float)h[3]);
  ((f16x4*)hi)[i] = h;
  ((f16x4*)lo)[i] = l;
}

// ---------------- plain cast: fp32 -> fp16 ----------------
__global__ __launch_bounds__(256) void cast_k(const float* __restrict__ in,
                                              f16* __restrict__ out,
                                              size_t n4) {
  size_t i = (size_t)blockIdx.x * 256 + threadIdx.x;
  if (i >= n4) return;
  float4 v = ((const float4*)in)[i];
  f16x4 h;
  h[0] = (f16)v.x; h[1] = (f16)v.y; h[2] = (f16)v.z; h[3] = (f16)v.w;
  ((f16x4*)out)[i] = h;
}

// ---------------- transpose+cast: x[b][s][d] fp32 -> xT[b][d][s] fp16 ------
__global__ __launch_bounds__(256) void transpose_cast_k(
    const float* __restrict__ x, f16* __restrict__ xT) {
  __shared__ f16 tile[32][33];
  const int b = blockIdx.z;
  const int s0 = blockIdx.x * 32, d0 = blockIdx.y * 32;
  const int tx = threadIdx.x & 31, ty = threadIdx.x >> 5;  // 32 x 8
  const float* xb = x + (size_t)b * Ss * Dd;
#pragma unroll
  for (int r = 0; r < 32; r += 8)
    tile[ty + r][tx] = (f16)xb[(size_t)(s0 + ty + r) * Dd + d0 + tx];
  __syncthreads();
  f16* xTb = xT + (size_t)b * Dd * Ss;
#pragma unroll
  for (int r = 0; r < 32; r += 8)
    xTb[(size_t)(d0 + ty + r) * Ss + s0 + tx] = tile[tx][ty + r];
}

// ---------------- stage ROWSx32 f16 tile in MFMA-fragment order ------------
// Panel p = 16 rows x 32 k = 1024B, stored so lane l holds element
// (row p*16+(l&15), k (l>>4)*8 .. +7) at panel_base + l*16.  Fragment
// reads are then ds_read_b128 at base+lane*16: zero bank conflicts
// (verified R2). Global side: 16 rows x 64B per instruction.
template <int PPW>  // panels staged per wave (tile rows = PPW*64)
__device__ __forceinline__ void stage_tile(const f16* __restrict__ g,
                                           size_t ld, f16* lds, int wave,
                                           int lane) {
#pragma unroll
  for (int c = 0; c < PPW; ++c) {
    int panel = wave * PPW + c;
    const f16* gp =
        g + (size_t)(panel * 16 + (lane & 15)) * ld + (lane >> 4) * 8;
    AS3 u32* lp = (AS3 u32*)(lds + panel * 512);
    __builtin_amdgcn_global_load_lds((const AS1 u32*)gp, lp, 16, 0, 0);
  }
}

// ---------------- batched C = A * B^T (+bias) ------------------------------
// DUAL_A: C = (A0 + A1) * B0^T (two A segments share one staged B tile).
// A: [M][K] f16, B: [N][K] f16, C fp32 [M][ldc] or f16 (OUT_F16).
// Block tile 128(M) x 256(N), BK=32; 4 waves 2x2, wave tile 64x128.
// Double-buffered LDS, one barrier per k-iter. grid: (N/256, M/128, batch).
template <bool DUAL_A, bool OUT_F16>
__global__ __launch_bounds__(256, 2) void gemm_bt(
    const f16* __restrict__ A0, const f16* __restrict__ A1,
    const f16* __restrict__ B0, float* __restrict__ C, f16* __restrict__ Ch,
    const float* __restrict__ bias, int K, size_t ldc, size_t sA, size_t sB,
    size_t sC) {
  const int tid = threadIdx.x;
  const int wave = tid >> 6, lane = tid & 63;
  const size_t tn = (size_t)blockIdx.x * 256;
  const size_t tm = (size_t)blockIdx.y * 128;
  const int b = blockIdx.z;

  constexpr int STAGE = (DUAL_A ? 4 : 3) * 4096;  // f16 elems per stage
  constexpr int BOFF = DUAL_A ? 8192 : 4096;      // Bs offset within stage
  __shared__ f16 smem[2 * STAGE];

  const f16* Ah = A0 + (size_t)b * sA + tm * (size_t)K;
  const f16* Al = DUAL_A ? (A1 + (size_t)b * sA + tm * (size_t)K) : nullptr;
  const f16* Bp = B0 + (size_t)b * sB + tn * (size_t)K;

  const int pA = (wave >> 1) * 4;  // A panels [pA, pA+4)   (64 rows)
  const int pB = (wave & 1) * 8;   // B panels [pB, pB+8)   (128 cols)

  auto stage_all = [&](int k, f16* buf) {
    stage_tile<2>(Ah + k, K, buf, wave, lane);
    if constexpr (DUAL_A) stage_tile<2>(Al + k, K, buf + 4096, wave, lane);
    stage_tile<4>(Bp + k, K, buf + BOFF, wave, lane);
  };

  f32x4 acc[4][8] = {};

  stage_all(0, smem);
  const int nIter = K / 32;
  for (int it = 0; it < nIter; ++it) {
    f16* cur = smem + (it & 1) * STAGE;
    f16* nxt = smem + ((it + 1) & 1) * STAGE;
    __syncthreads();  // drains vmcnt: waits on loads issued LAST iter (hidden)
    if (it + 1 < nIter) stage_all((it + 1) * 32, nxt);
    f16x8 ah[4], al[4];
#pragma unroll
    for (int i = 0; i < 4; ++i) {
      ah[i] = *(const f16x8*)&cur[(pA + i) * 512 + lane * 8];
      if constexpr (DUAL_A)
        al[i] = *(const f16x8*)&cur[4096 + (pA + i) * 512 + lane * 8];
    }
#pragma unroll
    for (int j = 0; j < 8; ++j) {
      f16x8 bf = *(const f16x8*)&cur[BOFF + (pB + j) * 512 + lane * 8];
#pragma unroll
      for (int i = 0; i < 4; ++i) {
        acc[i][j] =
            __builtin_amdgcn_mfma_f32_16x16x32_f16(ah[i], bf, acc[i][j], 0, 0, 0);
        if constexpr (DUAL_A)
          acc[i][j] = __builtin_amdgcn_mfma_f32_16x16x32_f16(al[i], bf,
                                                             acc[i][j], 0, 0, 0);
      }
    }
  }

  // epilogue: C/D layout col = lane&15, row = (lane>>4)*4 + reg
  const int wm = pA * 16, wn = pB * 16;
#pragma unroll
  for (int i = 0; i < 4; ++i) {
    size_t row0 = tm + wm + i * 16 + ((lane >> 4) << 2);
#pragma unroll
    for (int j = 0; j < 8; ++j) {
      size_t col = tn + wn + j * 16 + (lane & 15);
      float bj = bias ? bias[col] : 0.f;
#pragma unroll
      for (int r = 0; r < 4; ++r) {
        float v = acc[i][j][r] + bj;
        size_t off = (size_t)b * sC + (row0 + r) * ldc + col;
        if constexpr (OUT_F16)
          Ch[off] = (f16)v;
        else
          C[off] = v;
      }
    }
  }
}

// ---------------- row softmax (2048 cols), in-place fp32 + f16 copy --------
__global__ __launch_bounds__(256) void softmax_k(float* __restrict__ sc,
                                                 f16* __restrict__ wh) {
  const size_t row = blockIdx.x;
  float* p = sc + row * 2048;
  f16* w = wh + row * 2048;
  const int t = threadIdx.x;
  float4 v0 = ((const float4*)p)[t];
  float4 v1 = ((const float4*)p)[256 + t];
  float m = fmaxf(fmaxf(fmaxf(v0.x, v0.y), fmaxf(v0.z, v0.w)),
                  fmaxf(fmaxf(v1.x, v1.y), fmaxf(v1.z, v1.w)));
#pragma unroll
  for (int o = 32; o; o >>= 1) m = fmaxf(m, __shfl_xor(m, o, 64));
  __shared__ float red[4];
  if ((t & 63) == 0) red[t >> 6] = m;
  __syncthreads();
  m = fmaxf(fmaxf(red[0], red[1]), fmaxf(red[2], red[3]));
  v0.x = __expf(v0.x - m);
  v0.y = __expf(v0.y - m);
  v0.z = __expf(v0.z - m);
  v0.w = __expf(v0.w - m);
  v1.x = __expf(v1.x - m);
  v1.y = __expf(v1.y - m);
  v1.z = __expf(v1.z - m);
  v1.w = __expf(v1.w - m);
  float s = v0.x + v0.y + v0.z + v0.w + v1.x + v1.y + v1.z + v1.w;
#pragma unroll
  for (int o = 32; o; o >>= 1) s += __shfl_xor(s, o, 64);
  __shared__ float red2[4];
  if ((t & 63) == 0) red2[t >> 6] = s;
  __syncthreads();
  s = red2[0] + red2[1] + red2[2] + red2[3];
  float inv = 1.0f / s;
  v0.x *= inv; v0.y *= inv; v0.z *= inv; v0.w *= inv;
  v1.x *= inv; v1.y *= inv; v1.z *= inv; v1.w *= inv;
  ((float4*)p)[t] = v0;
  ((float4*)p)[256 + t] = v1;
  f16x4 h0, h1;
  h0[0] = (f16)v0.x; h0[1] = (f16)v0.y; h0[2] = (f16)v0.z; h0[3] = (f16)v0.w;
  h1[0] = (f16)v1.x; h1[1] = (f16)v1.y; h1[2] = (f16)v1.z; h1[3] = (f16)v1.w;
  ((f16x4*)w)[t] = h0;
  ((f16x4*)w)[256 + t] = h1;
}

extern "C" void kernel_launch(void* const* d_in, const int* in_sizes, int n_in,
                              void* d_out, int out_size, void* d_ws,
                              size_t ws_size, hipStream_t stream) {
  (void)in_sizes; (void)n_in; (void)out_size; (void)ws_size;
  const float* x = (const float*)d_in[0];     // [B,S,D]
  const float* W = (const float*)d_in[1];     // [D,D]
  const float* bias = (const float*)d_in[2];  // [D]
  float* ctx = (float*)d_out;                            // [B,S,D]
  float* scores = (float*)d_out + (size_t)Bb * Ss * Dd;  // [B,S,S]

  const size_t nBSD = (size_t)Bb * Ss * Dd;  // 16,777,216
  const size_t nDD = (size_t)Dd * Dd;        // 1,048,576

  f16* p = (f16*)d_ws;
  f16* x_hi = p; p += nBSD;
  f16* x_lo = p; p += nBSD;
  f16* xT   = p; p += nBSD;
  f16* W_hi = p; p += nDD;
  f16* p_hi = p; p += nBSD;
  // attnw [B,S,S] f16 aliases x_hi+x_lo (dead after GEMM2; exact size match)
  f16* attnw = x_hi;
  // total ws use: (4*nBSD + nDD)*2 bytes = ~136 MB

  // casts
  split_cast_k<<<(unsigned)(nBSD / 4 / 256), 256, 0, stream>>>(x, x_hi, x_lo,
                                                               nBSD / 4);
  cast_k<<<(unsigned)(nDD / 4 / 256), 256, 0, stream>>>(W, W_hi, nDD / 4);
  transpose_cast_k<<<dim3(Ss / 32, Dd / 32, Bb), 256, 0, stream>>>(x, xT);

  // GEMM1: proj = (x_hi + x_lo) @ W_hi^T + b -> f16   M=B*S, N=D, K=D
  gemm_bt<true, true><<<dim3(Dd / 256, (Bb * Ss) / 128, 1), 256, 0, stream>>>(
      x_hi, x_lo, W_hi, nullptr, p_hi, bias, Dd, (size_t)Dd, 0, 0, 0);

  // GEMM2: scores[b] = (x_hi + x_lo)[b] @ p_hi[b]^T -> fp32   M=N=S, K=D
  gemm_bt<true, false><<<dim3(Ss / 256, Ss / 128, Bb), 256, 0, stream>>>(
      x_hi, x_lo, p_hi, scores, nullptr, nullptr, Dd, (size_t)Ss,
      (size_t)Ss * Dd, (size_t)Ss * Dd, (size_t)Ss * Ss);

  // softmax rows, in-place fp32 + f16 copy (into attnw, aliasing dead x_hi)
  softmax_k<<<Bb * Ss, 256, 0, stream>>>(scores, attnw);

  // GEMM4: ctx[b] = attnw[b] @ xT[b]  (B = xT [D][S])   M=S, N=D, K=S
  gemm_bt<false, false><<<dim3(Dd / 256, Ss / 128, Bb), 256, 0, stream>>>(
      attnw, nullptr, xT, ctx, nullptr, nullptr, Ss, (size_t)Dd,
      (size_t)Ss * Ss, (size_t)Dd * Ss, (size_t)Ss * Dd);
}